// Round 10
// baseline (249.319 us; speedup 1.0000x reference)
//
#include <hip/hip_runtime.h>
#include <hip/hip_bf16.h>

#define B_   4
#define N_   16384
#define T_   65536
static constexpr float SCALE_F = 0.17677669529663687f; // 32^-0.5

typedef __attribute__((ext_vector_type(8))) short bf16x8;
typedef __attribute__((ext_vector_type(4))) float f32x4;

static __device__ __forceinline__ unsigned pk2bf(float lo, float hi) {
    __hip_bfloat162 t = __float22bfloat162_rn(make_float2(lo, hi));
    union { __hip_bfloat162 h; unsigned u; } c; c.h = t; return c.u;
}
static __device__ __forceinline__ unsigned short f2bf(float f) {
    unsigned u = __float_as_uint(f);
    u += 0x7fffu + ((u >> 16) & 1u);
    return (unsigned short)(u >> 16);
}
// 3-bit LDS swizzle key from row index (bits 0,1,3 -> x bits 0,1,2)
static __device__ __forceinline__ int swz(int n) {
    return (n & 3) | ((n >> 1) & 4);
}

// ---------------- prep: Wt_bf (3 blocks) + S1t/cvec (257 blocks) ------------
__global__ __launch_bounds__(256) void prep_all(
    const float* __restrict__ Wq, const float* __restrict__ Wk,
    const float* __restrict__ Wv, unsigned short* __restrict__ Wt,
    const float* __restrict__ Wr, const float* __restrict__ br,
    const float* __restrict__ Wout, const float* __restrict__ bout,
    float* __restrict__ S1t, float* __restrict__ cvec)
{
    const int blk = blockIdx.x;
    if (blk < 3) {
        const float* W = (blk == 0) ? Wq : (blk == 1) ? Wk : Wv;
        unsigned short* dst = Wt + (size_t)blk * 65536 + (size_t)threadIdx.x * 256;
        #pragma unroll 4
        for (int kb = 0; kb < 32; ++kb) {
            float v[8];
            #pragma unroll
            for (int e = 0; e < 8; ++e) v[e] = W[(kb*8 + e)*256 + threadIdx.x];
            uint4 w;
            w.x = pk2bf(v[0], v[1]); w.y = pk2bf(v[2], v[3]);
            w.z = pk2bf(v[4], v[5]); w.w = pk2bf(v[6], v[7]);
            *reinterpret_cast<uint4*>(dst + kb*8) = w;
        }
        return;
    }
    const int i = blk - 3, j = threadIdx.x;
    if (i < 256) {
        const int h = i >> 5, dd = i & 31;
        float s = 0.f;
        #pragma unroll 8
        for (int dp = 0; dp < 32; ++dp)
            s = fmaf(Wr[dd*32 + dp], Wout[(h*32 + dp)*256 + j], s);
        S1t[(size_t)j*256 + i] = s;
    } else {
        float cj = bout[j];
        for (int r = 0; r < 256; ++r) cj = fmaf(br[r & 31], Wout[r*256 + j], cj);
        cvec[j] = cj;
    }
}

// ---------------- K1: QKV projection — B-in-LDS, barrier-free A stream ------
// grid (512, 3), 512 thr / 8 waves (2 Mr x 4 Nc). Tile 128M x 256N, K=256.
// B: K-half (256n x 128k bf16 = 64KB) in LDS, swizzled, loaded once per phase.
// A: global->reg direct, f32->bf16 pack in reg. kk-loop: NO barriers/waits.
__global__ __launch_bounds__(512, 3) void proj_mfma(
    const float* __restrict__ states, const float* __restrict__ agent_qs,
    const float* __restrict__ obs, const unsigned short* __restrict__ Wt,
    const float* __restrict__ bq, const float* __restrict__ bk,
    const float* __restrict__ bv,
    unsigned short* __restrict__ q_bf, unsigned short* __restrict__ k_bf,
    unsigned short* __restrict__ v_bf)
{
    __shared__ __align__(16) unsigned short Bs[256*128];   // 64 KB

    const int tid = threadIdx.x;
    const int z  = blockIdx.y;
    const int t0 = blockIdx.x * 128;

    const float* X = (z == 0) ? states : (z == 1) ? agent_qs : obs;
    const unsigned short* Bt = Wt + (size_t)z * 65536;
    const float* bias = (z == 0) ? bq : (z == 1) ? bk : bv;
    unsigned short* Y = (z == 0) ? q_bf : (z == 1) ? k_bf : v_bf;
    const bool doabs = (z == 0);

    const int wid = tid >> 6, lane = tid & 63;
    const int l15 = lane & 15, g = lane >> 4;
    const int wr = wid >> 2, wc = wid & 3;

    // column permutation: frag coord n' -> true col c = [n'5][n'3:2][n'4][n'1:0]
    int ntrue[4];
    #pragma unroll
    for (int ni = 0; ni < 4; ++ni) {
        int np = ni*16 + l15;
        int c = (np & 32) | ((np & 12) << 1) | ((np & 16) >> 2) | (np & 3);
        ntrue[ni] = wc*64 + c;
    }

    // B half-load: 4096 16B-chunks, 8 per thread, swizzled placement
    auto loadBhalf = [&](int half) {
        #pragma unroll
        for (int rep = 0; rep < 8; ++rep) {
            int lin = rep*512 + tid;
            int n = lin >> 4, c = lin & 15;
            uint4 w = *reinterpret_cast<const uint4*>(
                Bt + (size_t)n*256 + half*128 + c*8);
            int x = c ^ swz(n);
            *reinterpret_cast<uint4*>(&Bs[n*128 + x*8]) = w;
        }
    };

    f32x4 acc[4][4];
    #pragma unroll
    for (int mi = 0; mi < 4; ++mi)
        #pragma unroll
        for (int ni = 0; ni < 4; ++ni) acc[mi][ni] = (f32x4){0.f,0.f,0.f,0.f};

    #pragma unroll
    for (int half = 0; half < 2; ++half) {
        if (half) __syncthreads();          // all reads of prev half done
        loadBhalf(half);
        __syncthreads();

        #pragma unroll
        for (int kk = 0; kk < 4; ++kk) {
            const int K0 = half*128 + kk*32;
            bf16x8 a[4], bb[4];
            #pragma unroll
            for (int mi = 0; mi < 4; ++mi) {
                int m = t0 + wr*64 + mi*16 + l15;
                const float* s = X + (size_t)m*256 + K0 + g*8;
                f32x4 lo = *reinterpret_cast<const f32x4*>(s);
                f32x4 hi = *reinterpret_cast<const f32x4*>(s + 4);
                union { unsigned u[4]; bf16x8 v; } cc;
                cc.u[0] = pk2bf(lo[0], lo[1]);
                cc.u[1] = pk2bf(lo[2], lo[3]);
                cc.u[2] = pk2bf(hi[0], hi[1]);
                cc.u[3] = pk2bf(hi[2], hi[3]);
                a[mi] = cc.v;
            }
            #pragma unroll
            for (int ni = 0; ni < 4; ++ni) {
                int n2 = ntrue[ni];
                int x = (kk*4 + g) ^ swz(n2);
                bb[ni] = *reinterpret_cast<const bf16x8*>(&Bs[n2*128 + x*8]);
            }
            #pragma unroll
            for (int mi = 0; mi < 4; ++mi)
                #pragma unroll
                for (int ni = 0; ni < 4; ++ni)
                    acc[mi][ni] = __builtin_amdgcn_mfma_f32_16x16x32_bf16(
                        bb[ni], a[mi], acc[mi][ni], 0, 0, 0);
        }
    }

    // epilogue: store s covers true cols wc*64 + s*32 + g*8 + [0,8)
    #pragma unroll
    for (int s = 0; s < 2; ++s) {
        int colb = wc*64 + s*32 + g*8;
        float4 b0 = *reinterpret_cast<const float4*>(bias + colb);
        float4 b1 = *reinterpret_cast<const float4*>(bias + colb + 4);
        #pragma unroll
        for (int mi = 0; mi < 4; ++mi) {
            int m = t0 + wr*64 + mi*16 + l15;
            float y0 = acc[mi][2*s  ][0] + b0.x;
            float y1 = acc[mi][2*s  ][1] + b0.y;
            float y2 = acc[mi][2*s  ][2] + b0.z;
            float y3 = acc[mi][2*s  ][3] + b0.w;
            float y4 = acc[mi][2*s+1][0] + b1.x;
            float y5 = acc[mi][2*s+1][1] + b1.y;
            float y6 = acc[mi][2*s+1][2] + b1.z;
            float y7 = acc[mi][2*s+1][3] + b1.w;
            if (doabs) {
                y0 = fabsf(y0); y1 = fabsf(y1); y2 = fabsf(y2); y3 = fabsf(y3);
                y4 = fabsf(y4); y5 = fabsf(y5); y6 = fabsf(y6); y7 = fabsf(y7);
            }
            uint4 pk;
            pk.x = pk2bf(y0, y1); pk.y = pk2bf(y2, y3);
            pk.z = pk2bf(y4, y5); pk.w = pk2bf(y6, y7);
            *reinterpret_cast<uint4*>(Y + (size_t)m*256 + colb) = pk;
        }
    }
}

// ---------------- pools: partial softmax pooling ----------------------------
__global__ __launch_bounds__(512) void pool_partial(
    const unsigned short* __restrict__ data,
    const float* __restrict__ wqa, const float* __restrict__ wka,
    const float* __restrict__ part_in, float* __restrict__ part_out, int mode)
{
    const int bh = blockIdx.x, ch = blockIdx.y;
    const int b = bh >> 3, h = bh & 7;
    const int tid = threadIdx.x;

    __shared__ float coef[32];
    __shared__ float s_red[8];
    __shared__ float a_red[8][32];

    if (tid < 32) {
        float cc;
        if (mode == 0) cc = wqa[tid];
        else {
            float num = 0.f, den = 0.f;
            #pragma unroll
            for (int c = 0; c < 8; ++c) {
                num += part_in[(size_t)(bh*8 + c)*40 + tid];
                den += part_in[(size_t)(bh*8 + c)*40 + 32];
            }
            cc = (num / den) * wka[tid];
        }
        coef[tid] = cc * SCALE_F;
    }
    __syncthreads();
    float cf[32];
    #pragma unroll
    for (int d = 0; d < 32; ++d) cf[d] = coef[d];

    float s = 0.f;
    float acc[32];
    #pragma unroll
    for (int d = 0; d < 32; ++d) acc[d] = 0.f;

    const unsigned short* base = data + (size_t)b * N_ * 256 + h * 32;
    for (int n = ch*2048 + tid; n < (ch + 1)*2048; n += 512) {
        const uint4* p = reinterpret_cast<const uint4*>(base + (size_t)n * 256);
        float qv[32];
        #pragma unroll
        for (int gg = 0; gg < 4; ++gg) {
            uint4 r = p[gg];
            unsigned w0 = r.x, w1 = r.y, w2 = r.z, w3 = r.w;
            qv[gg*8+0] = __uint_as_float(w0 << 16);
            qv[gg*8+1] = __uint_as_float(w0 & 0xffff0000u);
            qv[gg*8+2] = __uint_as_float(w1 << 16);
            qv[gg*8+3] = __uint_as_float(w1 & 0xffff0000u);
            qv[gg*8+4] = __uint_as_float(w2 << 16);
            qv[gg*8+5] = __uint_as_float(w2 & 0xffff0000u);
            qv[gg*8+6] = __uint_as_float(w3 << 16);
            qv[gg*8+7] = __uint_as_float(w3 & 0xffff0000u);
        }
        float l = 0.f;
        #pragma unroll
        for (int d = 0; d < 32; ++d) l = fmaf(qv[d], cf[d], l);
        float e = expf(l);
        s += e;
        #pragma unroll
        for (int d = 0; d < 32; ++d) acc[d] = fmaf(e, qv[d], acc[d]);
    }

    #pragma unroll
    for (int off = 1; off < 64; off <<= 1) {
        s += __shfl_xor(s, off);
        #pragma unroll
        for (int d = 0; d < 32; ++d) acc[d] += __shfl_xor(acc[d], off);
    }
    const int wave = tid >> 6, lane = tid & 63;
    if (lane == 0) {
        s_red[wave] = s;
        #pragma unroll
        for (int d = 0; d < 32; ++d) a_red[wave][d] = acc[d];
    }
    __syncthreads();
    if (tid < 32) {
        float num = 0.f, den = 0.f;
        #pragma unroll
        for (int w2 = 0; w2 < 8; ++w2) { num += a_red[w2][tid]; den += s_red[w2]; }
        part_out[(size_t)(bh*8 + ch)*40 + tid] = num;
        if (tid == 0) part_out[(size_t)(bh*8 + ch)*40 + 32] = den;
    }
}

// ---------------- Wcat_t[b][n][k] bf16 (gk computed inline from part_k) -----
__global__ __launch_bounds__(256) void build_wcat_t(
    const float* __restrict__ part_k, const float* __restrict__ S1t,
    const float* __restrict__ Wout, unsigned short* __restrict__ Wcat_t)
{
    const int b = blockIdx.x, n = blockIdx.y, k = threadIdx.x;
    const int h = k >> 5, d = k & 31;
    float num = 0.f, den = 0.f;
    #pragma unroll
    for (int c = 0; c < 8; ++c) {
        num += part_k[(size_t)((b*8 + h)*8 + c)*40 + d];
        den += part_k[(size_t)((b*8 + h)*8 + c)*40 + 32];
    }
    const float gkv = num / den;
    unsigned short* dst = Wcat_t + (size_t)(b*256 + n) * 512;
    dst[k]       = f2bf(gkv * S1t[(size_t)n*256 + k]);
    dst[k + 256] = f2bf(Wout[(size_t)k*256 + n]);
}

// ---------------- K4: out = [v|q] @ Wcat_t[b]^T + cvec ----------------------
// grid (512), 512 thr / 8 waves. Tile 128M x 256N, K=512 in 4 LDS quarters
// (256n x 128k bf16 = 64KB each). A: v (phases 0-1) / q (2-3) global->reg.
__global__ __launch_bounds__(512, 3) void out_mfma(
    const unsigned short* __restrict__ v_bf, const unsigned short* __restrict__ q_bf,
    const unsigned short* __restrict__ Wcat_t, const float* __restrict__ cvec,
    float* __restrict__ out)
{
    __shared__ __align__(16) unsigned short Bs[256*128];   // 64 KB

    const int tid = threadIdx.x;
    const int t0 = blockIdx.x * 128;
    const int b  = blockIdx.x >> 7;
    const unsigned short* Wb = Wcat_t + (size_t)b * 256 * 512;

    const int wid = tid >> 6, lane = tid & 63;
    const int l15 = lane & 15, g = lane >> 4;
    const int wr = wid >> 2, wc = wid & 3;

    auto loadBq = [&](int p) {
        #pragma unroll
        for (int rep = 0; rep < 8; ++rep) {
            int lin = rep*512 + tid;
            int n = lin >> 4, c = lin & 15;
            uint4 w = *reinterpret_cast<const uint4*>(
                Wb + (size_t)n*512 + p*128 + c*8);
            int x = c ^ swz(n);
            *reinterpret_cast<uint4*>(&Bs[n*128 + x*8]) = w;
        }
    };

    f32x4 acc[4][4];
    #pragma unroll
    for (int mi = 0; mi < 4; ++mi)
        #pragma unroll
        for (int ni = 0; ni < 4; ++ni) acc[mi][ni] = (f32x4){0.f,0.f,0.f,0.f};

    #pragma unroll
    for (int p = 0; p < 4; ++p) {
        if (p) __syncthreads();
        loadBq(p);
        __syncthreads();

        const unsigned short* src = (p < 2) ? v_bf : q_bf;
        const int ks = (p & 1) * 128;

        #pragma unroll
        for (int kl = 0; kl < 4; ++kl) {
            bf16x8 a[4], bb[4];
            #pragma unroll
            for (int mi = 0; mi < 4; ++mi) {
                int m = t0 + wr*64 + mi*16 + l15;
                a[mi] = *reinterpret_cast<const bf16x8*>(
                    src + (size_t)m*256 + ks + kl*32 + g*8);
            }
            #pragma unroll
            for (int ni = 0; ni < 4; ++ni) {
                int n2 = wc*64 + ni*16 + l15;
                int x = (kl*4 + g) ^ swz(n2);
                bb[ni] = *reinterpret_cast<const bf16x8*>(&Bs[n2*128 + x*8]);
            }
            #pragma unroll
            for (int mi = 0; mi < 4; ++mi)
                #pragma unroll
                for (int ni = 0; ni < 4; ++ni)
                    acc[mi][ni] = __builtin_amdgcn_mfma_f32_16x16x32_bf16(
                        bb[ni], a[mi], acc[mi][ni], 0, 0, 0);
        }
    }

    #pragma unroll
    for (int ni = 0; ni < 4; ++ni) {
        int colb = wc*64 + ni*16 + g*4;
        float4 cv = *reinterpret_cast<const float4*>(cvec + colb);
        #pragma unroll
        for (int mi = 0; mi < 4; ++mi) {
            int m = t0 + wr*64 + mi*16 + l15;
            float4 o;
            o.x = acc[mi][ni][0] + cv.x;
            o.y = acc[mi][ni][1] + cv.y;
            o.z = acc[mi][ni][2] + cv.z;
            o.w = acc[mi][ni][3] + cv.w;
            *reinterpret_cast<float4*>(out + (size_t)m*256 + colb) = o;
        }
    }
}

extern "C" void kernel_launch(void* const* d_in, const int* in_sizes, int n_in,
                              void* d_out, int out_size, void* d_ws, size_t ws_size,
                              hipStream_t stream)
{
    const float* states   = (const float*)d_in[0];
    const float* agent_qs = (const float*)d_in[1];
    const float* obs      = (const float*)d_in[2];
    const float* Wq   = (const float*)d_in[3];
    const float* bq   = (const float*)d_in[4];
    const float* Wk   = (const float*)d_in[5];
    const float* bk   = (const float*)d_in[6];
    const float* Wv   = (const float*)d_in[7];
    const float* bv   = (const float*)d_in[8];
    const float* wq_attn = (const float*)d_in[9];
    const float* wk_attn = (const float*)d_in[10];
    const float* Wr   = (const float*)d_in[11];
    const float* br   = (const float*)d_in[12];
    const float* Wout = (const float*)d_in[13];
    const float* bout = (const float*)d_in[14];
    float* out = (float*)d_out;

    char* w = (char*)d_ws;
    unsigned short* q_bf = (unsigned short*)w; w += (size_t)T_ * 256 * 2;
    unsigned short* k_bf = (unsigned short*)w; w += (size_t)T_ * 256 * 2;
    unsigned short* v_bf = (unsigned short*)w; w += (size_t)T_ * 256 * 2;
    unsigned short* Wt_bf   = (unsigned short*)w; w += (size_t)3 * 65536 * 2;
    unsigned short* Wcat_t  = (unsigned short*)w; w += (size_t)4 * 256 * 512 * 2;
    float* part_q = (float*)w; w += (size_t)256 * 40 * sizeof(float);
    float* part_k = (float*)w; w += (size_t)256 * 40 * sizeof(float);
    float* S1t  = (float*)w; w += (size_t)256 * 256 * sizeof(float);
    float* cvec = (float*)w; w += 256 * sizeof(float);

    prep_all<<<dim3(260), 256, 0, stream>>>(Wq, Wk, Wv, Wt_bf,
                                            Wr, br, Wout, bout, S1t, cvec);
    proj_mfma<<<dim3(512, 3), 512, 0, stream>>>(
        states, agent_qs, obs, Wt_bf, bq, bk, bv, q_bf, k_bf, v_bf);
    pool_partial<<<dim3(32, 8), 512, 0, stream>>>(q_bf, wq_attn, wk_attn,
                                                  part_q, part_q, 0);
    pool_partial<<<dim3(32, 8), 512, 0, stream>>>(k_bf, wq_attn, wk_attn,
                                                  part_q, part_k, 1);
    build_wcat_t<<<dim3(4, 256), 256, 0, stream>>>(part_k, S1t, Wout, Wcat_t);
    out_mfma<<<dim3(512), 512, 0, stream>>>(v_bf, q_bf, Wcat_t, cvec, out);
}

// Round 11
// 212.761 us; speedup vs baseline: 1.1718x; 1.1718x over previous
//
#include <hip/hip_runtime.h>
#include <hip/hip_bf16.h>

#define B_   4
#define N_   16384
#define T_   65536
static constexpr float SCALE_F = 0.17677669529663687f; // 32^-0.5

typedef __attribute__((ext_vector_type(8))) short bf16x8;
typedef __attribute__((ext_vector_type(4))) float f32x4;

static __device__ __forceinline__ unsigned pk2bf(float lo, float hi) {
    __hip_bfloat162 t = __float22bfloat162_rn(make_float2(lo, hi));
    union { __hip_bfloat162 h; unsigned u; } c; c.h = t; return c.u;
}
static __device__ __forceinline__ unsigned short f2bf(float f) {
    unsigned u = __float_as_uint(f);
    u += 0x7fffu + ((u >> 16) & 1u);
    return (unsigned short)(u >> 16);
}
// async global->LDS, 16B per lane; dst = wave-uniform base + lane*16
static __device__ __forceinline__ void gl_lds16(const void* g, void* l) {
    __builtin_amdgcn_global_load_lds(
        (const __attribute__((address_space(1))) unsigned int*)g,
        (__attribute__((address_space(3))) unsigned int*)l, 16, 0, 0);
}

// ---------------- prep: Wt_bf (3 blocks) + S1t/cvec (257 blocks) ------------
__global__ __launch_bounds__(256) void prep_all(
    const float* __restrict__ Wq, const float* __restrict__ Wk,
    const float* __restrict__ Wv, unsigned short* __restrict__ Wt,
    const float* __restrict__ Wr, const float* __restrict__ br,
    const float* __restrict__ Wout, const float* __restrict__ bout,
    float* __restrict__ S1t, float* __restrict__ cvec)
{
    const int blk = blockIdx.x;
    if (blk < 3) {
        const float* W = (blk == 0) ? Wq : (blk == 1) ? Wk : Wv;
        unsigned short* dst = Wt + (size_t)blk * 65536 + (size_t)threadIdx.x * 256;
        #pragma unroll 4
        for (int kb = 0; kb < 32; ++kb) {
            float v[8];
            #pragma unroll
            for (int e = 0; e < 8; ++e) v[e] = W[(kb*8 + e)*256 + threadIdx.x];
            uint4 w;
            w.x = pk2bf(v[0], v[1]); w.y = pk2bf(v[2], v[3]);
            w.z = pk2bf(v[4], v[5]); w.w = pk2bf(v[6], v[7]);
            *reinterpret_cast<uint4*>(dst + kb*8) = w;
        }
        return;
    }
    const int i = blk - 3, j = threadIdx.x;
    if (i < 256) {
        const int h = i >> 5, dd = i & 31;
        float s = 0.f;
        #pragma unroll 8
        for (int dp = 0; dp < 32; ++dp)
            s = fmaf(Wr[dd*32 + dp], Wout[(h*32 + dp)*256 + j], s);
        S1t[(size_t)j*256 + i] = s;
    } else {
        float cj = bout[j];
        for (int r = 0; r < 256; ++r) cj = fmaf(br[r & 31], Wout[r*256 + j], cj);
        cvec[j] = cj;
    }
}

// ---------------- K1: QKV projection — two-phase block ----------------------
// grid (1024, 3), 256 thr / 4 waves. Tile 64 M x 256 N, K=256.
// Phase 1: stage WHOLE A tile (64 rows x 1KB, 16 gl_lds16/wave, contiguous
//          row sources) + issue B half-0 register loads. ONE __syncthreads().
// Phase 2: 8 kk-steps of ds_read + cvt + MFMA. No barriers, no waits, no VMEM
//          (B half-1 reload is a register-dep load, compiler-scheduled).
// Cross-block TLP (2 blocks/CU) overlaps phase 1 of one block with phase 2
// of the other.
__global__ __launch_bounds__(256, 2) void proj_mfma(
    const float* __restrict__ states, const float* __restrict__ agent_qs,
    const float* __restrict__ obs, const unsigned short* __restrict__ Wt,
    const float* __restrict__ bq, const float* __restrict__ bk,
    const float* __restrict__ bv,
    unsigned short* __restrict__ q_bf, unsigned short* __restrict__ k_bf,
    unsigned short* __restrict__ v_bf)
{
    __shared__ __align__(16) float As[64][256];   // 64 KB, whole-K A tile

    const int tid = threadIdx.x;
    const int z  = blockIdx.y;
    const int t0 = blockIdx.x * 64;

    const float* X = (z == 0) ? states : (z == 1) ? agent_qs : obs;
    const unsigned short* Bt = Wt + (size_t)z * 65536;
    const float* bias = (z == 0) ? bq : (z == 1) ? bk : bv;
    unsigned short* Y = (z == 0) ? q_bf : (z == 1) ? k_bf : v_bf;
    const bool doabs = (z == 0);

    const int wid = tid >> 6, lane = tid & 63;
    const int l15 = lane & 15, g = lane >> 4;
    const int wc = wid;

    // column permutation: frag coord n' -> true col c = [n'5][n'3:2][n'4][n'1:0]
    const unsigned short* bbase[4];
    #pragma unroll
    for (int ni = 0; ni < 4; ++ni) {
        int np = ni*16 + l15;
        int c = (np & 32) | ((np & 12) << 1) | ((np & 16) >> 2) | (np & 3);
        bbase[ni] = Bt + (size_t)(wc*64 + c) * 256 + g*8;
    }

    bf16x8 breg[4][4];
    auto loadBhalf = [&](int half) {
        #pragma unroll
        for (int ni = 0; ni < 4; ++ni)
            #pragma unroll
            for (int sl = 0; sl < 4; ++sl)
                breg[ni][sl] = *reinterpret_cast<const bf16x8*>(
                    bbase[ni] + (half*4 + sl)*32);
    };

    // ---- Phase 1: whole-tile A staging (wave w -> rows w*16..w*16+15) ----
    // Row r source is ONE contiguous 1KB row; lane l fetches 16B chunk
    // l^(r&7), landing at LDS chunk l. So LDS chunk y holds src chunk y^(r&7).
    #pragma unroll
    for (int j = 0; j < 16; ++j) {
        int r = wid*16 + j;
        gl_lds16(X + (size_t)(t0 + r)*256 + ((lane ^ (r & 7)) << 2), &As[r][0]);
    }
    loadBhalf(0);
    __syncthreads();   // the block's ONE drain (vmcnt(0) + barrier)

    // ---- Phase 2: pure LDS + MFMA ----
    f32x4 acc[4][4];
    #pragma unroll
    for (int mi = 0; mi < 4; ++mi)
        #pragma unroll
        for (int ni = 0; ni < 4; ++ni) acc[mi][ni] = (f32x4){0.f,0.f,0.f,0.f};

    #pragma unroll
    for (int kk = 0; kk < 8; ++kk) {
        if (kk == 4) loadBhalf(1);          // register-dep load, no sync
        const int sl = kk & 3;
        bf16x8 a[4];
        #pragma unroll
        for (int mi = 0; mi < 4; ++mi) {
            int m = mi*16 + l15;
            int x = m & 7;
            int c0 = (kk*8 + 2*g) ^ x;
            int c1 = (kk*8 + 2*g + 1) ^ x;
            f32x4 lo = *reinterpret_cast<const f32x4*>(&As[m][c0 << 2]);
            f32x4 hi = *reinterpret_cast<const f32x4*>(&As[m][c1 << 2]);
            union { unsigned u[4]; bf16x8 v; } cc;
            cc.u[0] = pk2bf(lo[0], lo[1]);
            cc.u[1] = pk2bf(lo[2], lo[3]);
            cc.u[2] = pk2bf(hi[0], hi[1]);
            cc.u[3] = pk2bf(hi[2], hi[3]);
            a[mi] = cc.v;
        }
        #pragma unroll
        for (int mi = 0; mi < 4; ++mi)
            #pragma unroll
            for (int ni = 0; ni < 4; ++ni)
                acc[mi][ni] = __builtin_amdgcn_mfma_f32_16x16x32_bf16(
                    breg[ni][sl], a[mi], acc[mi][ni], 0, 0, 0);
    }

    // epilogue: store s covers true cols wc*64 + s*32 + g*8 + [0,8)
    #pragma unroll
    for (int s = 0; s < 2; ++s) {
        int colb = wc*64 + s*32 + g*8;
        float4 b0 = *reinterpret_cast<const float4*>(bias + colb);
        float4 b1 = *reinterpret_cast<const float4*>(bias + colb + 4);
        #pragma unroll
        for (int mi = 0; mi < 4; ++mi) {
            int m = t0 + mi*16 + l15;
            float y0 = acc[mi][2*s  ][0] + b0.x;
            float y1 = acc[mi][2*s  ][1] + b0.y;
            float y2 = acc[mi][2*s  ][2] + b0.z;
            float y3 = acc[mi][2*s  ][3] + b0.w;
            float y4 = acc[mi][2*s+1][0] + b1.x;
            float y5 = acc[mi][2*s+1][1] + b1.y;
            float y6 = acc[mi][2*s+1][2] + b1.z;
            float y7 = acc[mi][2*s+1][3] + b1.w;
            if (doabs) {
                y0 = fabsf(y0); y1 = fabsf(y1); y2 = fabsf(y2); y3 = fabsf(y3);
                y4 = fabsf(y4); y5 = fabsf(y5); y6 = fabsf(y6); y7 = fabsf(y7);
            }
            uint4 pk;
            pk.x = pk2bf(y0, y1); pk.y = pk2bf(y2, y3);
            pk.z = pk2bf(y4, y5); pk.w = pk2bf(y6, y7);
            *reinterpret_cast<uint4*>(Y + (size_t)m*256 + colb) = pk;
        }
    }
}

// ---------------- pools: partial softmax pooling ----------------------------
__global__ __launch_bounds__(512) void pool_partial(
    const unsigned short* __restrict__ data,
    const float* __restrict__ wqa, const float* __restrict__ wka,
    const float* __restrict__ part_in, float* __restrict__ part_out, int mode)
{
    const int bh = blockIdx.x, ch = blockIdx.y;
    const int b = bh >> 3, h = bh & 7;
    const int tid = threadIdx.x;

    __shared__ float coef[32];
    __shared__ float s_red[8];
    __shared__ float a_red[8][32];

    if (tid < 32) {
        float cc;
        if (mode == 0) cc = wqa[tid];
        else {
            float num = 0.f, den = 0.f;
            #pragma unroll
            for (int c = 0; c < 8; ++c) {
                num += part_in[(size_t)(bh*8 + c)*40 + tid];
                den += part_in[(size_t)(bh*8 + c)*40 + 32];
            }
            cc = (num / den) * wka[tid];
        }
        coef[tid] = cc * SCALE_F;
    }
    __syncthreads();
    float cf[32];
    #pragma unroll
    for (int d = 0; d < 32; ++d) cf[d] = coef[d];

    float s = 0.f;
    float acc[32];
    #pragma unroll
    for (int d = 0; d < 32; ++d) acc[d] = 0.f;

    const unsigned short* base = data + (size_t)b * N_ * 256 + h * 32;
    for (int n = ch*2048 + tid; n < (ch + 1)*2048; n += 512) {
        const uint4* p = reinterpret_cast<const uint4*>(base + (size_t)n * 256);
        float qv[32];
        #pragma unroll
        for (int gg = 0; gg < 4; ++gg) {
            uint4 r = p[gg];
            unsigned w0 = r.x, w1 = r.y, w2 = r.z, w3 = r.w;
            qv[gg*8+0] = __uint_as_float(w0 << 16);
            qv[gg*8+1] = __uint_as_float(w0 & 0xffff0000u);
            qv[gg*8+2] = __uint_as_float(w1 << 16);
            qv[gg*8+3] = __uint_as_float(w1 & 0xffff0000u);
            qv[gg*8+4] = __uint_as_float(w2 << 16);
            qv[gg*8+5] = __uint_as_float(w2 & 0xffff0000u);
            qv[gg*8+6] = __uint_as_float(w3 << 16);
            qv[gg*8+7] = __uint_as_float(w3 & 0xffff0000u);
        }
        float l = 0.f;
        #pragma unroll
        for (int d = 0; d < 32; ++d) l = fmaf(qv[d], cf[d], l);
        float e = expf(l);
        s += e;
        #pragma unroll
        for (int d = 0; d < 32; ++d) acc[d] = fmaf(e, qv[d], acc[d]);
    }

    #pragma unroll
    for (int off = 1; off < 64; off <<= 1) {
        s += __shfl_xor(s, off);
        #pragma unroll
        for (int d = 0; d < 32; ++d) acc[d] += __shfl_xor(acc[d], off);
    }
    const int wave = tid >> 6, lane = tid & 63;
    if (lane == 0) {
        s_red[wave] = s;
        #pragma unroll
        for (int d = 0; d < 32; ++d) a_red[wave][d] = acc[d];
    }
    __syncthreads();
    if (tid < 32) {
        float num = 0.f, den = 0.f;
        #pragma unroll
        for (int w2 = 0; w2 < 8; ++w2) { num += a_red[w2][tid]; den += s_red[w2]; }
        part_out[(size_t)(bh*8 + ch)*40 + tid] = num;
        if (tid == 0) part_out[(size_t)(bh*8 + ch)*40 + 32] = den;
    }
}

// ---------------- Wcat_t[b][n][k] bf16 (gk computed inline from part_k) -----
__global__ __launch_bounds__(256) void build_wcat_t(
    const float* __restrict__ part_k, const float* __restrict__ S1t,
    const float* __restrict__ Wout, unsigned short* __restrict__ Wcat_t)
{
    const int b = blockIdx.x, n = blockIdx.y, k = threadIdx.x;
    const int h = k >> 5, d = k & 31;
    float num = 0.f, den = 0.f;
    #pragma unroll
    for (int c = 0; c < 8; ++c) {
        num += part_k[(size_t)((b*8 + h)*8 + c)*40 + d];
        den += part_k[(size_t)((b*8 + h)*8 + c)*40 + 32];
    }
    const float gkv = num / den;
    unsigned short* dst = Wcat_t + (size_t)(b*256 + n) * 512;
    dst[k]       = f2bf(gkv * S1t[(size_t)n*256 + k]);
    dst[k + 256] = f2bf(Wout[(size_t)k*256 + n]);
}

// ---------------- K4: out = [v|q] @ Wcat_t[b]^T + cvec — two-phase ----------
// grid (1024), 256 thr / 4 waves. Tile 64 M x 256 N, K=512 (v 0..255 | q ..511).
// Phase 1: stage whole [v|q] tile (32KB+32KB bf16, 16 gl_lds16/wave, each op
//          covers TWO contiguous 512B rows) + B half-0 regs. One sync.
// Phase 2: 16 kk-steps, no barriers; B half-1 reload at kk=8.
__global__ __launch_bounds__(256, 2) void out_mfma(
    const unsigned short* __restrict__ v_bf, const unsigned short* __restrict__ q_bf,
    const unsigned short* __restrict__ Wcat_t, const float* __restrict__ cvec,
    float* __restrict__ out)
{
    __shared__ __align__(16) unsigned short Av[64][256];  // 32 KB
    __shared__ __align__(16) unsigned short Aq[64][256];  // 32 KB

    const int tid = threadIdx.x;
    const int t0 = blockIdx.x * 64;
    const int b  = t0 >> 14;
    const unsigned short* Wb = Wcat_t + (size_t)b * 256 * 512;

    const int wid = tid >> 6, lane = tid & 63;
    const int l15 = lane & 15, g = lane >> 4, wc = wid;

    const unsigned short* bbase[4];
    #pragma unroll
    for (int ni = 0; ni < 4; ++ni)
        bbase[ni] = Wb + (size_t)(wc*64 + ni*16 + l15) * 512 + g*8;

    bf16x8 breg[4][8];
    auto loadBhalf = [&](int half) {
        #pragma unroll
        for (int ni = 0; ni < 4; ++ni)
            #pragma unroll
            for (int sl = 0; sl < 8; ++sl)
                breg[ni][sl] = *reinterpret_cast<const bf16x8*>(
                    bbase[ni] + (half*8 + sl)*32);
    };

    // ---- Phase 1 ----
    // Each op: 2 consecutive rows (1KB contiguous). lane l -> row 2j+(l>>5),
    // 16B chunk (l&31)^(row&7) of that row; lands at LDS chunk (l&31).
    #pragma unroll
    for (int j = 0; j < 8; ++j) {
        int r0 = wid*16 + 2*j;
        {
            int r = r0 + 0;   // lanes 0-31 cover row r0, 32-63 row r0+1
            gl_lds16(v_bf + (size_t)(t0 + r0 + (lane >> 5))*256
                          + (((lane & 31) ^ ((r0 + (lane >> 5)) & 7)) << 3),
                     &Av[r0][0]);
            (void)r;
        }
        gl_lds16(q_bf + (size_t)(t0 + r0 + (lane >> 5))*256
                      + (((lane & 31) ^ ((r0 + (lane >> 5)) & 7)) << 3),
                 &Aq[r0][0]);
    }
    loadBhalf(0);
    __syncthreads();

    // ---- Phase 2 ----
    f32x4 acc[4][4];
    #pragma unroll
    for (int mi = 0; mi < 4; ++mi)
        #pragma unroll
        for (int ni = 0; ni < 4; ++ni) acc[mi][ni] = (f32x4){0.f,0.f,0.f,0.f};

    #pragma unroll
    for (int kk = 0; kk < 16; ++kk) {
        if (kk == 8) loadBhalf(1);
        const int sl = kk & 7;
        const unsigned short (*Asrc)[256] = (kk < 8) ? Av : Aq;
        bf16x8 a[4];
        #pragma unroll
        for (int mi = 0; mi < 4; ++mi) {
            int m = mi*16 + l15;
            int c = (((kk & 7)*4 + g) ^ (m & 7));
            a[mi] = *reinterpret_cast<const bf16x8*>(&Asrc[m][c << 3]);
        }
        #pragma unroll
        for (int mi = 0; mi < 4; ++mi)
            #pragma unroll
            for (int ni = 0; ni < 4; ++ni)
                acc[mi][ni] = __builtin_amdgcn_mfma_f32_16x16x32_bf16(
                    breg[ni][sl], a[mi], acc[mi][ni], 0, 0, 0);
    }

    #pragma unroll
    for (int ni = 0; ni < 4; ++ni) {
        int colb = wc*64 + ni*16 + g*4;
        float4 cv = *reinterpret_cast<const float4*>(cvec + colb);
        #pragma unroll
        for (int mi = 0; mi < 4; ++mi) {
            int m = t0 + mi*16 + l15;
            float4 o;
            o.x = acc[mi][ni][0] + cv.x;
            o.y = acc[mi][ni][1] + cv.y;
            o.z = acc[mi][ni][2] + cv.z;
            o.w = acc[mi][ni][3] + cv.w;
            *reinterpret_cast<float4*>(out + (size_t)m*256 + colb) = o;
        }
    }
}

extern "C" void kernel_launch(void* const* d_in, const int* in_sizes, int n_in,
                              void* d_out, int out_size, void* d_ws, size_t ws_size,
                              hipStream_t stream)
{
    const float* states   = (const float*)d_in[0];
    const float* agent_qs = (const float*)d_in[1];
    const float* obs      = (const float*)d_in[2];
    const float* Wq   = (const float*)d_in[3];
    const float* bq   = (const float*)d_in[4];
    const float* Wk   = (const float*)d_in[5];
    const float* bk   = (const float*)d_in[6];
    const float* Wv   = (const float*)d_in[7];
    const float* bv   = (const float*)d_in[8];
    const float* wq_attn = (const float*)d_in[9];
    const float* wk_attn = (const float*)d_in[10];
    const float* Wr   = (const float*)d_in[11];
    const float* br   = (const float*)d_in[12];
    const float* Wout = (const float*)d_in[13];
    const float* bout = (const float*)d_in[14];
    float* out = (float*)d_out;

    char* w = (char*)d_ws;
    unsigned short* q_bf = (unsigned short*)w; w += (size_t)T_ * 256 * 2;
    unsigned short* k_bf = (unsigned short*)w; w += (size_t)T_ * 256 * 2;
    unsigned short* v_bf = (unsigned short*)w; w += (size_t)T_ * 256 * 2;
    unsigned short* Wt_bf   = (unsigned short*)w; w += (size_t)3 * 65536 * 2;
    unsigned short* Wcat_t  = (unsigned short*)w; w += (size_t)4 * 256 * 512 * 2;
    float* part_q = (float*)w; w += (size_t)256 * 40 * sizeof(float);
    float* part_k = (float*)w; w += (size_t)256 * 40 * sizeof(float);
    float* S1t  = (float*)w; w += (size_t)256 * 256 * sizeof(float);
    float* cvec = (float*)w; w += 256 * sizeof(float);

    prep_all<<<dim3(260), 256, 0, stream>>>(Wq, Wk, Wv, Wt_bf,
                                            Wr, br, Wout, bout, S1t, cvec);
    proj_mfma<<<dim3(1024, 3), 256, 0, stream>>>(
        states, agent_qs, obs, Wt_bf, bq, bk, bv, q_bf, k_bf, v_bf);
    pool_partial<<<dim3(32, 8), 512, 0, stream>>>(q_bf, wq_attn, wk_attn,
                                                  part_q, part_q, 0);
    pool_partial<<<dim3(32, 8), 512, 0, stream>>>(k_bf, wq_attn, wk_attn,
                                                  part_q, part_k, 1);
    build_wcat_t<<<dim3(4, 256), 256, 0, stream>>>(part_k, S1t, Wout, Wcat_t);
    out_mfma<<<dim3(1024), 256, 0, stream>>>(v_bf, q_bf, Wcat_t, cvec, out);
}